// Round 1
// baseline (91.226 us; speedup 1.0000x reference)
//
#include <hip/hip_runtime.h>
#include <float.h>

// Problem constants (match reference)
#define BB 8
#define LL 2048
#define DD 256
#define TT 32
// tasks: 0..7 topic | 8..71 para(64) | 72..263 shell(192) | 264..455 x(192)
#define N_TASKS 456

__global__ __launch_bounds__(256) void max_extract_kernel(
    const float* __restrict__ topic_reps,   // [B,T,D]
    const float* __restrict__ word_reps,    // [B,L,D]
    const int*   __restrict__ para_spans,   // [B,8,3]
    const int*   __restrict__ x_spans,      // [B,24,3]
    const int*   __restrict__ shell_spans,  // [B,24,3]
    float* __restrict__ out)                // topic(2048) | para(16384) | shell(49152) | x(49152)
{
    const int wave = threadIdx.x >> 6;
    const int lane = threadIdx.x & 63;
    const int task = blockIdx.x * 4 + wave;
    if (task >= N_TASKS) return;

    const float* src;
    float*       dst;
    int          rows;

    if (task < 8) {
        const int b = task;
        src  = topic_reps + b * TT * DD;
        rows = TT;
        dst  = out + b * DD;
    } else if (task < 72) {
        const int idx = task - 8;                       // b*8+s
        const int* sp = para_spans + idx * 3;
        const int elmo = sp[0], start = sp[1], end = sp[2];
        src  = word_reps + ((size_t)elmo * LL + start) * DD;
        rows = end - start + 1;                          // end inclusive, >=1
        dst  = out + 2048 + idx * DD;
    } else if (task < 264) {
        const int idx = task - 72;                      // shell -> span_reps
        const int* sp = shell_spans + idx * 3;
        const int elmo = sp[0], start = sp[1], end = sp[2];
        src  = word_reps + ((size_t)elmo * LL + start) * DD;
        rows = end - start + 1;
        dst  = out + 2048 + 16384 + idx * DD;
    } else {
        const int idx = task - 264;                     // x -> adu_reps
        const int* sp = x_spans + idx * 3;
        const int elmo = sp[0], start = sp[1], end = sp[2];
        src  = word_reps + ((size_t)elmo * LL + start) * DD;
        rows = end - start + 1;
        dst  = out + 2048 + 16384 + 49152 + idx * DD;
    }

    // lane l owns dims [4l, 4l+4): fully coalesced float4 stream, stride D floats
    const float4* p = reinterpret_cast<const float4*>(src) + lane;
    float4 acc = p[0];
    #pragma unroll 4
    for (int r = 1; r < rows; ++r) {
        const float4 v = p[r * (DD / 4)];
        acc.x = fmaxf(acc.x, v.x);
        acc.y = fmaxf(acc.y, v.y);
        acc.z = fmaxf(acc.z, v.z);
        acc.w = fmaxf(acc.w, v.w);
    }
    reinterpret_cast<float4*>(dst)[lane] = acc;
}

extern "C" void kernel_launch(void* const* d_in, const int* in_sizes, int n_in,
                              void* d_out, int out_size, void* d_ws, size_t ws_size,
                              hipStream_t stream) {
    const float* topic_reps  = (const float*)d_in[0];
    const float* word_reps   = (const float*)d_in[1];
    // d_in[2] = topic_lens (int64) — unused by the reference computation
    const int*   para_spans  = (const int*)d_in[3];
    const int*   x_spans     = (const int*)d_in[4];
    const int*   shell_spans = (const int*)d_in[5];
    float*       out         = (float*)d_out;

    const int blocks = (N_TASKS + 3) / 4;   // 114
    max_extract_kernel<<<blocks, 256, 0, stream>>>(
        topic_reps, word_reps, para_spans, x_spans, shell_spans, out);
}

// Round 2
// 74.554 us; speedup vs baseline: 1.2236x; 1.2236x over previous
//
#include <hip/hip_runtime.h>
#include <float.h>

// Problem constants (match reference)
#define BB 8
#define LL 2048
#define DD 256
#define TT 32
// tasks: 0..7 topic | 8..71 para(64) | 72..263 shell(192) | 264..455 x(192)
#define N_TASKS 456
#define NWAVES 8   // 512 threads

__global__ __launch_bounds__(512) void max_extract_kernel(
    const float* __restrict__ topic_reps,   // [B,T,D]
    const float* __restrict__ word_reps,    // [B,L,D]
    const int*   __restrict__ para_spans,   // [B,8,3]
    const int*   __restrict__ x_spans,      // [B,24,3]
    const int*   __restrict__ shell_spans,  // [B,24,3]
    float* __restrict__ out)                // topic(2048) | para(16384) | shell(49152) | x(49152)
{
    const int wave = threadIdx.x >> 6;
    const int lane = threadIdx.x & 63;
    const int task = blockIdx.x;

    const float* src;
    float*       dst;
    int          rows;

    if (task < 8) {
        const int b = task;
        src  = topic_reps + b * TT * DD;
        rows = TT;
        dst  = out + b * DD;
    } else if (task < 72) {
        const int idx = task - 8;                       // b*8+s
        const int* sp = para_spans + idx * 3;
        const int elmo = sp[0], start = sp[1], end = sp[2];
        src  = word_reps + ((size_t)elmo * LL + start) * DD;
        rows = end - start + 1;                          // end inclusive, >=1
        dst  = out + 2048 + idx * DD;
    } else if (task < 264) {
        const int idx = task - 72;                      // shell -> span_reps
        const int* sp = shell_spans + idx * 3;
        const int elmo = sp[0], start = sp[1], end = sp[2];
        src  = word_reps + ((size_t)elmo * LL + start) * DD;
        rows = end - start + 1;
        dst  = out + 2048 + 16384 + idx * DD;
    } else {
        const int idx = task - 264;                     // x -> adu_reps
        const int* sp = x_spans + idx * 3;
        const int elmo = sp[0], start = sp[1], end = sp[2];
        src  = word_reps + ((size_t)elmo * LL + start) * DD;
        rows = end - start + 1;
        dst  = out + 2048 + 16384 + 49152 + idx * DD;
    }

    // Each wave handles rows wave, wave+8, ... ; lane l owns dims [4l,4l+4).
    // Fully coalesced: each row access is one 1 KB wave transaction.
    const float4* p = reinterpret_cast<const float4*>(src) + lane;
    float4 acc = make_float4(-FLT_MAX, -FLT_MAX, -FLT_MAX, -FLT_MAX);
    #pragma unroll 4
    for (int r = wave; r < rows; r += NWAVES) {
        const float4 v = p[r * (DD / 4)];
        acc.x = fmaxf(acc.x, v.x);
        acc.y = fmaxf(acc.y, v.y);
        acc.z = fmaxf(acc.z, v.z);
        acc.w = fmaxf(acc.w, v.w);
    }

    // Cross-wave max reduce via LDS: [wave][lane] float4
    __shared__ float4 red[NWAVES][64];
    red[wave][lane] = acc;
    __syncthreads();

    if (wave == 0) {
        float4 m = red[0][lane];
        #pragma unroll
        for (int w = 1; w < NWAVES; ++w) {
            const float4 v = red[w][lane];
            m.x = fmaxf(m.x, v.x);
            m.y = fmaxf(m.y, v.y);
            m.z = fmaxf(m.z, v.z);
            m.w = fmaxf(m.w, v.w);
        }
        reinterpret_cast<float4*>(dst)[lane] = m;
    }
}

extern "C" void kernel_launch(void* const* d_in, const int* in_sizes, int n_in,
                              void* d_out, int out_size, void* d_ws, size_t ws_size,
                              hipStream_t stream) {
    const float* topic_reps  = (const float*)d_in[0];
    const float* word_reps   = (const float*)d_in[1];
    // d_in[2] = topic_lens (int64) — unused by the reference computation
    const int*   para_spans  = (const int*)d_in[3];
    const int*   x_spans     = (const int*)d_in[4];
    const int*   shell_spans = (const int*)d_in[5];
    float*       out         = (float*)d_out;

    max_extract_kernel<<<N_TASKS, 512, 0, stream>>>(
        topic_reps, word_reps, para_spans, x_spans, shell_spans, out);
}